// Round 1
// baseline (867.266 us; speedup 1.0000x reference)
//
#include <hip/hip_runtime.h>
#include <math.h>

// Problem constants (fixed by setup_inputs)
constexpr int B_ = 8;
constexpr int N_ = 2048;
constexpr int D_ = 256;
constexpr int H_ = 16;
constexpr int K_ = 8;

// ---------------------------------------------------------------------------
// Kernel 1: inverse norms for f1 and f2 rows: 1/(||x|| + 1e-8)
// One wave (64 lanes) per row; 2*B*N rows total.
// ---------------------------------------------------------------------------
__global__ __launch_bounds__(256)
void norm_kernel(const float* __restrict__ f1, const float* __restrict__ f2,
                 float* __restrict__ inv1, float* __restrict__ inv2) {
    int gid  = blockIdx.x * blockDim.x + threadIdx.x;
    int wave = gid >> 6;
    int lane = gid & 63;
    if (wave >= 2 * B_ * N_) return;
    bool is1 = wave < B_ * N_;
    int row = is1 ? wave : wave - B_ * N_;
    const float* r = (is1 ? f1 : f2) + (size_t)row * D_;
    float ss = 0.f;
#pragma unroll
    for (int j = 0; j < D_ / 64; j++) {
        float v = r[lane + 64 * j];
        ss += v * v;
    }
#pragma unroll
    for (int off = 32; off > 0; off >>= 1) ss += __shfl_xor(ss, off, 64);
    if (lane == 0) (is1 ? inv1 : inv2)[row] = 1.0f / (sqrtf(ss) + 1e-8f);
}

// ---------------------------------------------------------------------------
// Kernel 2: fused cosine-sim GEMM + coord distance + pointwise MLP -> w
// Block computes a 64x64 tile of w[b, q, p]. 256 threads, 4x4 outputs each.
// w1 = f2n[q] . f1n[p]  (normalization folded in via inv norms)
// w2 = -max(||q||^2 + ||p||^2 - 2 q.p, 0)
// w  = b2 + sum_h W2[h] * relu(W1[h,0]*w1 + W1[h,1]*w2 + b1[h])
// ---------------------------------------------------------------------------
constexpr int TS = 64;
constexpr int KC = 16;

__global__ __launch_bounds__(256)
void gemm_mlp_kernel(const float* __restrict__ f1, const float* __restrict__ f2,
                     const float* __restrict__ pc, const float* __restrict__ qc,
                     const float* __restrict__ inv1, const float* __restrict__ inv2,
                     const float* __restrict__ pW1, const float* __restrict__ pb1,
                     const float* __restrict__ pW2, const float* __restrict__ pb2,
                     float* __restrict__ w_out) {
    __shared__ float As[KC][TS + 1];
    __shared__ float Bs[KC][TS + 1];
    __shared__ float sW1[2 * H_];
    __shared__ float sb1[H_];
    __shared__ float sW2[H_];
    __shared__ float sb2;

    int tid = threadIdx.x;
    int tx = tid & 15, ty = tid >> 4;
    int pBase = blockIdx.x * TS;
    int qBase = blockIdx.y * TS;
    int b = blockIdx.z;

    if (tid < 2 * H_) sW1[tid] = pW1[tid];
    else if (tid < 3 * H_) sb1[tid - 2 * H_] = pb1[tid - 2 * H_];
    else if (tid < 4 * H_) sW2[tid - 3 * H_] = pW2[tid - 3 * H_];
    else if (tid == 4 * H_) sb2 = pb2[0];

    // staging mapping: each thread loads one float4 of A-tile and B-tile
    int li  = tid >> 2;   // tile row 0..63
    int lk4 = tid & 3;    // which float4 within the 16-wide K chunk
    float ia = inv2[b * N_ + qBase + li];  // A = f2 rows (query dim)
    float ib = inv1[b * N_ + pBase + li];  // B = f1 rows (point dim)
    const float* Abase = f2 + ((size_t)(b * N_ + qBase) + li) * D_;
    const float* Bbase = f1 + ((size_t)(b * N_ + pBase) + li) * D_;

    float acc[4][4] = {};

    for (int kb = 0; kb < D_; kb += KC) {
        __syncthreads();  // previous iteration's LDS reads complete
        float4 av = *(const float4*)(Abase + kb + lk4 * 4);
        float4 bv = *(const float4*)(Bbase + kb + lk4 * 4);
        As[lk4 * 4 + 0][li] = av.x * ia;
        As[lk4 * 4 + 1][li] = av.y * ia;
        As[lk4 * 4 + 2][li] = av.z * ia;
        As[lk4 * 4 + 3][li] = av.w * ia;
        Bs[lk4 * 4 + 0][li] = bv.x * ib;
        Bs[lk4 * 4 + 1][li] = bv.y * ib;
        Bs[lk4 * 4 + 2][li] = bv.z * ib;
        Bs[lk4 * 4 + 3][li] = bv.w * ib;
        __syncthreads();
#pragma unroll
        for (int k = 0; k < KC; k++) {
            float a0 = As[k][ty * 4 + 0];
            float a1 = As[k][ty * 4 + 1];
            float a2 = As[k][ty * 4 + 2];
            float a3 = As[k][ty * 4 + 3];
            float b0 = Bs[k][tx +  0];
            float b1 = Bs[k][tx + 16];
            float b2 = Bs[k][tx + 32];
            float b3 = Bs[k][tx + 48];
            acc[0][0] += a0 * b0; acc[0][1] += a0 * b1; acc[0][2] += a0 * b2; acc[0][3] += a0 * b3;
            acc[1][0] += a1 * b0; acc[1][1] += a1 * b1; acc[1][2] += a1 * b2; acc[1][3] += a1 * b3;
            acc[2][0] += a2 * b0; acc[2][1] += a2 * b1; acc[2][2] += a2 * b2; acc[2][3] += a2 * b3;
            acc[3][0] += a3 * b0; acc[3][1] += a3 * b1; acc[3][2] += a3 * b2; acc[3][3] += a3 * b3;
        }
    }

    // epilogue: coord term + MLP + store
    float qx[4], qy[4], qz[4], qq[4];
#pragma unroll
    for (int ii = 0; ii < 4; ii++) {
        int ig = qBase + ty * 4 + ii;
        const float* qp = qc + ((size_t)(b * N_ + ig)) * 3;
        qx[ii] = qp[0]; qy[ii] = qp[1]; qz[ii] = qp[2];
        qq[ii] = qx[ii] * qx[ii] + qy[ii] * qy[ii] + qz[ii] * qz[ii];
    }
#pragma unroll
    for (int jj = 0; jj < 4; jj++) {
        int jg = pBase + tx + 16 * jj;
        const float* pp = pc + ((size_t)(b * N_ + jg)) * 3;
        float px = pp[0], py = pp[1], pz = pp[2];
        float pn = px * px + py * py + pz * pz;
#pragma unroll
        for (int ii = 0; ii < 4; ii++) {
            float w1v = acc[ii][jj];
            float d2 = qq[ii] + pn - 2.f * (qx[ii] * px + qy[ii] * py + qz[ii] * pz);
            float w2v = -fmaxf(d2, 0.f);
            float out = sb2;
#pragma unroll
            for (int h = 0; h < H_; h++) {
                float t = sW1[2 * h] * w1v + sW1[2 * h + 1] * w2v + sb1[h];
                out += sW2[h] * fmaxf(t, 0.f);
            }
            int ig = qBase + ty * 4 + ii;
            w_out[((size_t)(b * N_ + ig)) * N_ + jg] = out;
        }
    }
}

// ---------------------------------------------------------------------------
// Kernel 3: per-row top-8 (desc, stable: smaller index wins ties) + softmax
// + gather f1 rows + weighted-sum & max pooling. One wave per (b,q) row.
// ---------------------------------------------------------------------------
__global__ __launch_bounds__(256)
void topk_kernel(const float* __restrict__ w, const float* __restrict__ f1,
                 float* __restrict__ f_out, float* __restrict__ idx_out) {
    int gid  = blockIdx.x * blockDim.x + threadIdx.x;
    int row  = gid >> 6;
    int lane = gid & 63;
    if (row >= B_ * N_) return;
    int b = row >> 11;  // row / N_
    const float* wrow = w + (size_t)row * N_;

    // per-lane sorted top-8 over strided elements (indices ascending per lane)
    float tv[K_];
    int   ti[K_];
#pragma unroll
    for (int s = 0; s < K_; s++) { tv[s] = -INFINITY; ti[s] = 0x7fffffff; }
    for (int j = 0; j < N_ / 64; j++) {
        int idx = lane + 64 * j;
        float v = wrow[idx];
        if (v > tv[K_ - 1]) {   // strict >: stable (earlier index kept on tie)
            tv[K_ - 1] = v; ti[K_ - 1] = idx;
#pragma unroll
            for (int s = K_ - 1; s > 0; s--) {
                if (tv[s] > tv[s - 1]) {
                    float tf = tv[s]; tv[s] = tv[s - 1]; tv[s - 1] = tf;
                    int tn = ti[s]; ti[s] = ti[s - 1]; ti[s - 1] = tn;
                }
            }
        }
    }

    // 8 rounds of cross-lane argmax (prefer larger value, then smaller index)
    float outv[K_];
    int   outi[K_];
#pragma unroll
    for (int r = 0; r < K_; r++) {
        float bv = tv[0];
        int   bi = ti[0];
#pragma unroll
        for (int off = 1; off < 64; off <<= 1) {
            float ov = __shfl_xor(bv, off, 64);
            int   oi = __shfl_xor(bi, off, 64);
            if (ov > bv || (ov == bv && oi < bi)) { bv = ov; bi = oi; }
        }
        outv[r] = bv; outi[r] = bi;
        if (ti[0] == bi) {  // this lane supplied the winner: pop it
#pragma unroll
            for (int s = 0; s < K_ - 1; s++) { tv[s] = tv[s + 1]; ti[s] = ti[s + 1]; }
            tv[K_ - 1] = -INFINITY; ti[K_ - 1] = 0x7fffffff;
        }
    }

    // softmax over the 8 gathered scores
    float m = outv[0];
    float e[K_], s = 0.f;
#pragma unroll
    for (int r = 0; r < K_; r++) { e[r] = expf(outv[r] - m); s += e[r]; }
    float inv_s = 1.f / s;

    // gather + pool
    const float* f1b = f1 + ((size_t)b * N_) * D_;
    size_t obase = (size_t)row * (2 * D_);
#pragma unroll
    for (int jd = 0; jd < D_ / 64; jd++) {
        int d = lane + 64 * jd;
        float accv = 0.f, mx = -INFINITY;
#pragma unroll
        for (int r = 0; r < K_; r++) {
            float x = f1b[(size_t)outi[r] * D_ + d];
            accv += (e[r] * inv_s) * x;
            mx = fmaxf(mx, x);
        }
        f_out[obase + d]      = accv;
        f_out[obase + D_ + d] = mx;
    }
    if (lane == 0) {
#pragma unroll
        for (int r = 0; r < K_; r++) idx_out[(size_t)row * K_ + r] = (float)outi[r];
    }
}

// ---------------------------------------------------------------------------
extern "C" void kernel_launch(void* const* d_in, const int* in_sizes, int n_in,
                              void* d_out, int out_size, void* d_ws, size_t ws_size,
                              hipStream_t stream) {
    const float* f1 = (const float*)d_in[0];
    const float* f2 = (const float*)d_in[1];
    const float* pc = (const float*)d_in[2];
    const float* qc = (const float*)d_in[3];
    const float* W1 = (const float*)d_in[4];
    const float* b1 = (const float*)d_in[5];
    const float* W2 = (const float*)d_in[6];
    const float* b2 = (const float*)d_in[7];
    // similar_num (d_in[8]) is fixed at 8

    float* out     = (float*)d_out;
    float* f_out   = out;                                   // [B,N,2D]
    float* idx_out = f_out + (size_t)B_ * N_ * 2 * D_;      // [B,N,K] as float
    float* w_out   = idx_out + (size_t)B_ * N_ * K_;        // [B,N,N]

    float* inv1 = (float*)d_ws;        // [B*N]
    float* inv2 = inv1 + B_ * N_;      // [B*N]

    norm_kernel<<<(2 * B_ * N_) / 4, 256, 0, stream>>>(f1, f2, inv1, inv2);

    dim3 g2(N_ / TS, N_ / TS, B_);
    gemm_mlp_kernel<<<g2, 256, 0, stream>>>(f1, f2, pc, qc, inv1, inv2,
                                            W1, b1, W2, b2, w_out);

    topk_kernel<<<(B_ * N_) / 4, 256, 0, stream>>>(w_out, f1, f_out, idx_out);
}